// Round 4
// baseline (271.894 us; speedup 1.0000x reference)
//
#include <hip/hip_runtime.h>
#include <hip/hip_bf16.h>

#define TPB 256
#define SH 6
#define BW 64  // nodes per bucket = 1<<SH; NBUK must be <= 1024 (N <= 65536)

typedef unsigned short u16;
typedef __attribute__((ext_vector_type(8))) __bf16 bf16x8;  // MFMA A/B frag (4 VGPRs)
typedef __attribute__((ext_vector_type(4))) float f32x4;    // MFMA C/D frag

// bf16 helpers: payload stored as bf16 (halves gather BW), accumulate in fp32.
__device__ __forceinline__ u16 f_to_bf(float f) {
    unsigned u = __float_as_uint(f);
    return (u16)((u + 0x7fff + ((u >> 16) & 1)) >> 16);  // RNE
}
__device__ __forceinline__ float4 bf4_to_f4(ushort4 v) {
    float4 r;
    r.x = __uint_as_float((unsigned)v.x << 16);
    r.y = __uint_as_float((unsigned)v.y << 16);
    r.z = __uint_as_float((unsigned)v.z << 16);
    r.w = __uint_as_float((unsigned)v.w << 16);
    return r;
}
__device__ __forceinline__ void facc(float4& a, float4 v) {
    a.x += v.x; a.y += v.y; a.z += v.z; a.w += v.w;
}
__device__ __forceinline__ float4 shfl_xor4(float4 v, int mask, int width) {
    v.x = __shfl_xor(v.x, mask, width);
    v.y = __shfl_xor(v.y, mask, width);
    v.z = __shfl_xor(v.z, mask, width);
    v.w = __shfl_xor(v.w, mask, width);
    return v;
}

// XCD-aware block swizzle (4 XCDs per graph): blk&7 = XCD on MI355X.
__device__ __forceinline__ bool swz_block(int nblk, int& g, int& bx) {
    int blk = blockIdx.x;
    int j = blk & 7;
    g = j >> 2;
    bx = (blk >> 3) * 4 + (j & 3);
    return bx < nblk;
}

// Software-pipelined gather (8B/lane): load 8 indices, issue 8 row-gathers into a
// register array, THEN accumulate (depth-8 MLP; round-1 best config).
template <int C>
__device__ __forceinline__ float4 gather_sum(const u16* __restrict__ HW,
                                             const int* __restrict__ col,
                                             int c0, int ps, int pe) {
    float4 a0 = make_float4(0.f, 0.f, 0.f, 0.f);
    float4 a1 = a0, a2 = a0, a3 = a0;
    int p = ps;
    for (; p + 8 <= pe; p += 8) {
        int j[8];
        ushort4 d[8];
#pragma unroll
        for (int k = 0; k < 8; k++) j[k] = col[p + k];
#pragma unroll
        for (int k = 0; k < 8; k++) d[k] = *(const ushort4*)&HW[(size_t)j[k] * C + c0];
        facc(a0, bf4_to_f4(d[0])); facc(a1, bf4_to_f4(d[1]));
        facc(a2, bf4_to_f4(d[2])); facc(a3, bf4_to_f4(d[3]));
        facc(a0, bf4_to_f4(d[4])); facc(a1, bf4_to_f4(d[5]));
        facc(a2, bf4_to_f4(d[6])); facc(a3, bf4_to_f4(d[7]));
    }
    if (p + 4 <= pe) {
        int j[4];
        ushort4 d[4];
#pragma unroll
        for (int k = 0; k < 4; k++) j[k] = col[p + k];
#pragma unroll
        for (int k = 0; k < 4; k++) d[k] = *(const ushort4*)&HW[(size_t)j[k] * C + c0];
        facc(a0, bf4_to_f4(d[0])); facc(a1, bf4_to_f4(d[1]));
        facc(a2, bf4_to_f4(d[2])); facc(a3, bf4_to_f4(d[3]));
        p += 4;
    }
    for (; p < pe; p++) {
        int j = col[p];
        facc(a0, bf4_to_f4(*(const ushort4*)&HW[(size_t)j * C + c0]));
    }
    facc(a0, a1); facc(a2, a3); facc(a0, a2);
    return a0;
}

// ---------------- capacity-bucket CSR build (no count/scan passes) ----------------

__global__ void bucket_scatter_kernel(const int* __restrict__ e0, const int* __restrict__ e1,
                                      int E, int* __restrict__ bcur,
                                      int* __restrict__ ebuf0, int* __restrict__ ebuf1,
                                      int nbuk, int cap) {
    int g = blockIdx.y;
    const int* src = g ? e1 : e0;
    const int* dst = src + E;
    int* ebuf = g ? ebuf1 : ebuf0;
    int* bu = bcur + g * 1024;
    __shared__ int hist[1024];
    for (int t = threadIdx.x; t < 1024; t += TPB) hist[t] = 0;
    __syncthreads();
    int base = blockIdx.x * 4096;
    int pk[16], bk[16], rk[16];
#pragma unroll
    for (int k = 0; k < 16; k++) {
        int e = base + k * TPB + (int)threadIdx.x;
        bk[k] = -1;
        if (e < E) {
            int s = src[e], d = dst[e];
            int b = d >> SH;
            bk[k] = b;
            pk[k] = (s << SH) | (d & (BW - 1));
            rk[k] = atomicAdd(&hist[b], 1);
        }
    }
    __syncthreads();
    for (int t = threadIdx.x; t < nbuk; t += TPB) {
        int h = hist[t];
        hist[t] = h ? atomicAdd(&bu[t], h) : 0;
    }
    __syncthreads();
#pragma unroll
    for (int k = 0; k < 16; k++)
        if (bk[k] >= 0) {
            int pos = hist[bk[k]] + rk[k];
            if (pos < cap) ebuf[(size_t)bk[k] * cap + pos] = pk[k];
        }
}

// Per-bucket: histogram -> local scan -> soff/eoff/dinv -> fill col (bucket-local).
__global__ void bucket_csr_kernel(const int* __restrict__ ebuf0, const int* __restrict__ ebuf1,
                                  const int* __restrict__ bcur, int n, int cap,
                                  int* __restrict__ soff0, int* __restrict__ soff1,
                                  int* __restrict__ eoff0, int* __restrict__ eoff1,
                                  float* __restrict__ dinv0, float* __restrict__ dinv1,
                                  int* __restrict__ col0, int* __restrict__ col1) {
    int g = blockIdx.y;
    int b = blockIdx.x;
    const int* ebuf = g ? ebuf1 : ebuf0;
    int* soff = g ? soff1 : soff0;
    int* eoff = g ? eoff1 : eoff0;
    float* dinv = g ? dinv1 : dinv0;
    int* col = g ? col1 : col0;
    __shared__ int h[BW], nb[BW], nrank[BW];
    int tid = threadIdx.x;
    if (tid < BW) h[tid] = 0;
    __syncthreads();
    int s = b * cap;
    int cnt = min(bcur[g * 1024 + b], cap);
    int e = s + cnt;
    for (int i = s + tid; i < e; i += TPB)
        atomicAdd(&h[ebuf[i] & (BW - 1)], 1);
    __syncthreads();
    if (tid < BW) {
        int v = h[tid];
        int x = v;
        for (int d = 1; d < BW; d <<= 1) {
            int u = __shfl_up(x, d, 64);
            if (tid >= d) x += u;
        }
        int base = s + x - v;  // exclusive prefix within bucket region
        nb[tid] = base;
        nrank[tid] = 0;
        int node = b * BW + tid;
        if (node < n) {
            soff[node] = base;
            eoff[node] = base + v;
            dinv[node] = rsqrtf((float)v + 1.0f);
        }
    }
    __syncthreads();
    for (int i = s + tid; i < e; i += TPB) {
        int p = ebuf[i];
        int lo = p & (BW - 1);
        int r = atomicAdd(&nrank[lo], 1);
        col[nb[lo] + r] = p >> SH;
    }
}

// ------- dense matmul via MFMA: Y = bf16( dinv[n] * (X @ W) ), fp32 input -------
// PLANES: output stored as two channel-half planes [2][n][COUT/2] so the layer-1
// gather's per-XCD working set (one plane, 3.2 MB) fits the 4 MiB XCD L2.

template <int CIN, int COUT, bool PLANES>
__global__ void matmul_kernel(const float* __restrict__ X0, const float* __restrict__ X1,
                              const float* __restrict__ W,
                              const float* __restrict__ dinv0, const float* __restrict__ dinv1,
                              u16* __restrict__ Y0, u16* __restrict__ Y1, int n) {
    constexpr int CINP = CIN + 8;
    constexpr int NT = COUT / 16;
    constexpr int KT = CIN / 32;
    __shared__ u16 Xs[64 * CINP];
    __shared__ u16 Wt[COUT * CINP];

    int g = blockIdx.y;
    const float* X = g ? X1 : X0;
    const float* dinv = g ? dinv1 : dinv0;
    u16* Y = g ? Y1 : Y0;
    int nb0 = blockIdx.x * 64;

    for (int i = threadIdx.x; i < 64 * (CIN / 4); i += TPB) {
        int nn = i / (CIN / 4), kc = i % (CIN / 4);
        float4 v = make_float4(0.f, 0.f, 0.f, 0.f);
        if (nb0 + nn < n) v = *(const float4*)&X[(size_t)(nb0 + nn) * CIN + 4 * kc];
        ushort4 b;
        b.x = f_to_bf(v.x); b.y = f_to_bf(v.y); b.z = f_to_bf(v.z); b.w = f_to_bf(v.w);
        *(ushort4*)&Xs[nn * CINP + 4 * kc] = b;
    }
    for (int i = threadIdx.x; i < CIN * (COUT / 4); i += TPB) {
        int k = i / (COUT / 4), nc4 = i % (COUT / 4);
        float4 v = *(const float4*)&W[(size_t)k * COUT + 4 * nc4];
        Wt[(4 * nc4 + 0) * CINP + k] = f_to_bf(v.x);
        Wt[(4 * nc4 + 1) * CINP + k] = f_to_bf(v.y);
        Wt[(4 * nc4 + 2) * CINP + k] = f_to_bf(v.z);
        Wt[(4 * nc4 + 3) * CINP + k] = f_to_bf(v.w);
    }
    __syncthreads();

    int lane = threadIdx.x & 63;
    int w = threadIdx.x >> 6;
    int m = lane & 15;
    int quad = lane >> 4;

    f32x4 acc[NT];
#pragma unroll
    for (int t = 0; t < NT; t++) acc[t] = (f32x4){0.f, 0.f, 0.f, 0.f};
#pragma unroll
    for (int kt = 0; kt < KT; kt++) {
        int k0 = kt * 32 + quad * 8;
        bf16x8 a = *(const bf16x8*)&Xs[(w * 16 + m) * CINP + k0];
#pragma unroll
        for (int t = 0; t < NT; t++) {
            bf16x8 b = *(const bf16x8*)&Wt[(t * 16 + m) * CINP + k0];
            acc[t] = __builtin_amdgcn_mfma_f32_16x16x32_bf16(a, b, acc[t], 0, 0, 0);
        }
    }
#pragma unroll
    for (int r = 0; r < 4; r++) {
        int node = nb0 + w * 16 + quad * 4 + r;
        if (node < n) {
            float d = dinv[node];
#pragma unroll
            for (int t = 0; t < NT; t++) {
                if constexpr (PLANES) {
                    size_t idx = (size_t)(t >> 1) * ((size_t)n * (COUT / 2)) +
                                 (size_t)node * (COUT / 2) + (t & 1) * 16 + m;
                    Y[idx] = f_to_bf(acc[t][r] * d);
                } else {
                    Y[(size_t)node * COUT + t * 16 + m] = f_to_bf(acc[t][r] * d);
                }
            }
        }
    }
}

// ------- bf16-input MFMA matmul: Y = bf16( dinv * (H @ W) ), contiguous out -------

template <int CIN, int COUT>
__global__ void matmul_bf_kernel(const u16* __restrict__ X0, const u16* __restrict__ X1,
                                 const float* __restrict__ W,
                                 const float* __restrict__ dinv0, const float* __restrict__ dinv1,
                                 u16* __restrict__ Y0, u16* __restrict__ Y1, int n) {
    constexpr int CINP = CIN + 8;
    constexpr int NT = COUT / 16;
    constexpr int KT = CIN / 32;
    __shared__ u16 Xs[64 * CINP];
    __shared__ u16 Wt[COUT * CINP];

    int g = blockIdx.y;
    const u16* X = g ? X1 : X0;
    const float* dinv = g ? dinv1 : dinv0;
    u16* Y = g ? Y1 : Y0;
    int nb0 = blockIdx.x * 64;

    for (int i = threadIdx.x; i < 64 * (CIN / 8); i += TPB) {
        int nn = i / (CIN / 8), kc = i % (CIN / 8);
        ulonglong2 v = {0ull, 0ull};
        if (nb0 + nn < n) v = *(const ulonglong2*)&X[(size_t)(nb0 + nn) * CIN + 8 * kc];
        *(ulonglong2*)&Xs[nn * CINP + 8 * kc] = v;
    }
    for (int i = threadIdx.x; i < CIN * (COUT / 4); i += TPB) {
        int k = i / (COUT / 4), nc4 = i % (COUT / 4);
        float4 v = *(const float4*)&W[(size_t)k * COUT + 4 * nc4];
        Wt[(4 * nc4 + 0) * CINP + k] = f_to_bf(v.x);
        Wt[(4 * nc4 + 1) * CINP + k] = f_to_bf(v.y);
        Wt[(4 * nc4 + 2) * CINP + k] = f_to_bf(v.z);
        Wt[(4 * nc4 + 3) * CINP + k] = f_to_bf(v.w);
    }
    __syncthreads();

    int lane = threadIdx.x & 63;
    int w = threadIdx.x >> 6;
    int m = lane & 15;
    int quad = lane >> 4;

    f32x4 acc[NT];
#pragma unroll
    for (int t = 0; t < NT; t++) acc[t] = (f32x4){0.f, 0.f, 0.f, 0.f};
#pragma unroll
    for (int kt = 0; kt < KT; kt++) {
        int k0 = kt * 32 + quad * 8;
        bf16x8 a = *(const bf16x8*)&Xs[(w * 16 + m) * CINP + k0];
#pragma unroll
        for (int t = 0; t < NT; t++) {
            bf16x8 b = *(const bf16x8*)&Wt[(t * 16 + m) * CINP + k0];
            acc[t] = __builtin_amdgcn_mfma_f32_16x16x32_bf16(a, b, acc[t], 0, 0, 0);
        }
    }
#pragma unroll
    for (int r = 0; r < 4; r++) {
        int node = nb0 + w * 16 + quad * 4 + r;
        if (node < n) {
            float d = dinv[node];
#pragma unroll
            for (int t = 0; t < NT; t++)
                Y[(size_t)node * COUT + t * 16 + m] = f_to_bf(acc[t][r] * d);
        }
    }
}

// ------- layer-1 agg, channel-plane split (no LDS, no epilogue) -------
// XCD k serves combo (g = k>>2, ch = (k>>1)&1): gathers from plane [g][ch] (N x 32
// bf16 = 3.2 MB, L2-resident per XCD) and writes relu'd bf16 H1 half-rows.

__global__ __launch_bounds__(TPB, 2)
void agg_split_kernel(const u16* __restrict__ P0, const u16* __restrict__ P1,
                      const int* __restrict__ soff0, const int* __restrict__ soff1,
                      const int* __restrict__ eoff0, const int* __restrict__ eoff1,
                      const int* __restrict__ col0, const int* __restrict__ col1,
                      const float* __restrict__ dinv0, const float* __restrict__ dinv1,
                      const float* __restrict__ bias,
                      u16* __restrict__ H0, u16* __restrict__ H1, int n, int nblk) {
    int blk = blockIdx.x;
    int xcd = blk & 7;
    int g = xcd >> 2;
    int ch = (xcd >> 1) & 1;
    int bx = (blk >> 3) * 2 + (xcd & 1);
    if (bx >= nblk) return;
    const u16* P = (g ? P1 : P0) + (size_t)ch * n * 32;
    const int* soff = g ? soff1 : soff0;
    const int* eoff = g ? eoff1 : eoff0;
    const int* col = g ? col1 : col0;
    const float* dinv = g ? dinv1 : dinv0;
    u16* H = g ? H1 : H0;

    int nl = threadIdx.x >> 4;    // node in block (16 nodes/block)
    int part = threadIdx.x & 15;  // 2 slices x 8 lanes (4 ch each)
    int sp = part >> 3;
    int c0 = (part & 7) * 4;
    int node = bx * 16 + nl;
    if (node >= n) return;

    int s = soff[node], e = eoff[node];
    int len = e - s;
    int chunk = (len + 1) >> 1;
    int ps = s + sp * chunk;
    int pe = min(ps + chunk, e);
    float4 r = gather_sum<32>(P, col, c0, ps, pe);
    facc(r, shfl_xor4(r, 8, 16));
    if (sp == 0) {
        float di = dinv[node];
        float4 self = bf4_to_f4(*(const ushort4*)&P[(size_t)node * 32 + c0]);
        float4 b4 = *(const float4*)&bias[ch * 32 + c0];
        float4 o;
        o.x = fmaxf(di * (r.x + self.x) + b4.x, 0.f);
        o.y = fmaxf(di * (r.y + self.y) + b4.y, 0.f);
        o.z = fmaxf(di * (r.z + self.z) + b4.z, 0.f);
        o.w = fmaxf(di * (r.w + self.w) + b4.w, 0.f);
        ushort4 hb;
        hb.x = f_to_bf(o.x); hb.y = f_to_bf(o.y); hb.z = f_to_bf(o.z); hb.w = f_to_bf(o.w);
        *(ushort4*)&H[(size_t)node * 64 + ch * 32 + c0] = hb;
    }
}

// ------- fused GCN agg (C channels, bf16 payload) + MFMA next-layer matmul -------
// Used for layer 2 (payload 3.2 MB/graph: L2-resident with 4-XCD graph split).

template <int C, int SPLIT, int COUT2>
__global__ __launch_bounds__(TPB, 2)
void agg_mm_kernel(const u16* __restrict__ HW0, const u16* __restrict__ HW1,
                   const int* __restrict__ soff0, const int* __restrict__ soff1,
                   const int* __restrict__ eoff0, const int* __restrict__ eoff1,
                   const int* __restrict__ col0, const int* __restrict__ col1,
                   const float* __restrict__ dinv0, const float* __restrict__ dinv1,
                   const float* __restrict__ bias, const float* __restrict__ W2,
                   u16* __restrict__ Y0, u16* __restrict__ Y1, int n, int nblk) {
    constexpr int CH = C / 4;        // lanes covering one row (4 ch / 8B each)
    constexpr int TPN = CH * SPLIT;  // 16
    constexpr int CP = C + 8;        // padded LDS row stride (u16); keeps 16B align
    constexpr int NT2 = COUT2 / 16;  // MFMA col-tiles (waves used in epilogue)
    constexpr int KT2 = C / 32;      // MFMA k-tiles
    __shared__ __align__(16) u16 HsB[16 * CP];
    __shared__ __align__(16) u16 WtB[COUT2 * CP];

    int g, bx;
    if (!swz_block(nblk, g, bx)) return;
    const u16* HW = g ? HW1 : HW0;
    const int* soff = g ? soff1 : soff0;
    const int* eoff = g ? eoff1 : eoff0;
    const int* col = g ? col1 : col0;
    const float* dinv = g ? dinv1 : dinv0;
    u16* Y = g ? Y1 : Y0;

    // stage W2 transposed (bf16) while gather loads are in flight
    for (int idx = threadIdx.x; idx < C * COUT2; idx += TPB) {
        int k = idx / COUT2, nc = idx % COUT2;
        WtB[nc * CP + k] = f_to_bf(W2[idx]);
    }

    int tid = bx * TPB + (int)threadIdx.x;
    int node = tid / TPN;
    int nl = threadIdx.x / TPN;
    int part = threadIdx.x % TPN;
    int sp = part / CH;
    int c0 = (part % CH) * 4;
    float4 o = make_float4(0.f, 0.f, 0.f, 0.f);
    if (node < n) {
        int s = soff[node], e = eoff[node];
        int len = e - s;
        int chunk = (len + SPLIT - 1) / SPLIT;
        int ps = s + sp * chunk;
        int pe = min(ps + chunk, e);
        float4 r = gather_sum<C>(HW, col, c0, ps, pe);
#pragma unroll
        for (int m = CH; m < TPN; m <<= 1) facc(r, shfl_xor4(r, m, TPN));
        if (sp == 0) {
            float di = dinv[node];
            float4 self = bf4_to_f4(*(const ushort4*)&HW[(size_t)node * C + c0]);
            float4 b4 = *(const float4*)&bias[c0];
            o.x = fmaxf(di * (r.x + self.x) + b4.x, 0.f);
            o.y = fmaxf(di * (r.y + self.y) + b4.y, 0.f);
            o.z = fmaxf(di * (r.z + self.z) + b4.z, 0.f);
            o.w = fmaxf(di * (r.w + self.w) + b4.w, 0.f);
        }
    }
    if (sp == 0) {  // zeros for tail nodes
        ushort4 hb;
        hb.x = f_to_bf(o.x); hb.y = f_to_bf(o.y); hb.z = f_to_bf(o.z); hb.w = f_to_bf(o.w);
        *(ushort4*)&HsB[nl * CP + c0] = hb;
    }
    __syncthreads();

    // MFMA epilogue: wave w computes 16 nodes x out-cols [w*16, w*16+16)
    int lane = threadIdx.x & 63;
    int w = threadIdx.x >> 6;
    if (w < NT2) {
        int m = lane & 15;
        int quad = lane >> 4;
        f32x4 acc = (f32x4){0.f, 0.f, 0.f, 0.f};
#pragma unroll
        for (int kt = 0; kt < KT2; kt++) {
            int k0 = kt * 32 + quad * 8;
            bf16x8 a = *(const bf16x8*)&HsB[m * CP + k0];
            bf16x8 b = *(const bf16x8*)&WtB[(w * 16 + m) * CP + k0];
            acc = __builtin_amdgcn_mfma_f32_16x16x32_bf16(a, b, acc, 0, 0, 0);
        }
        int base16 = bx * 16;
#pragma unroll
        for (int r = 0; r < 4; r++) {
            int onode = base16 + quad * 4 + r;
            if (onode < n)
                Y[(size_t)onode * COUT2 + w * 16 + m] = f_to_bf(acc[r] * dinv[onode]);
        }
    }
}

// Layer-3 aggregation (C=16, SPLIT=4) + per-block colsum partials (NO atomics).
__global__ __launch_bounds__(TPB, 2)
void agg16_kernel(const u16* __restrict__ HW0, const u16* __restrict__ HW1,
                  const int* __restrict__ soff0, const int* __restrict__ soff1,
                  const int* __restrict__ eoff0, const int* __restrict__ eoff1,
                  const int* __restrict__ col0, const int* __restrict__ col1,
                  const float* __restrict__ dinv0, const float* __restrict__ dinv1,
                  const float* __restrict__ bias,
                  float* __restrict__ out0, float* __restrict__ out1,
                  float* __restrict__ pcol, int n, int nblk) {
    int g, bx;
    if (!swz_block(nblk, g, bx)) return;
    const u16* HW = g ? HW1 : HW0;
    const int* soff = g ? soff1 : soff0;
    const int* eoff = g ? eoff1 : eoff0;
    const int* col = g ? col1 : col0;
    const float* dinv = g ? dinv1 : dinv0;
    float* outp = g ? out1 : out0;
    int tid = bx * TPB + (int)threadIdx.x;
    int node = tid / 16;
    int part = tid % 16;
    int sp = part / 4;
    int c0 = (part % 4) * 4;
    float4 o = make_float4(0.f, 0.f, 0.f, 0.f);
    if (node < n) {
        int s = soff[node], e = eoff[node];
        int len = e - s;
        int chunk = (len + 3) / 4;
        int ps = s + sp * chunk;
        int pe = min(ps + chunk, e);
        float4 r = gather_sum<16>(HW, col, c0, ps, pe);
        facc(r, shfl_xor4(r, 4, 16));
        facc(r, shfl_xor4(r, 8, 16));
        if (sp == 0) {
            float di = dinv[node];
            float4 self = bf4_to_f4(*(const ushort4*)&HW[(size_t)node * 16 + c0]);
            float4 b4 = *(const float4*)&bias[c0];
            o.x = di * (r.x + self.x) + b4.x;
            o.y = di * (r.y + self.y) + b4.y;
            o.z = di * (r.z + self.z) + b4.z;
            o.w = di * (r.w + self.w) + b4.w;
            *(float4*)&outp[(size_t)node * 16 + c0] = o;
        }
    }
    // per-block colsum partial (only sp==0 lanes hold data)
    __shared__ float4 sd[TPB];
    sd[threadIdx.x] = (node < n && sp == 0) ? o : make_float4(0.f, 0.f, 0.f, 0.f);
    __syncthreads();
    if (threadIdx.x < 64) {
        float4 a = sd[threadIdx.x];
        facc(a, sd[threadIdx.x + 64]);
        facc(a, sd[threadIdx.x + 128]);
        facc(a, sd[threadIdx.x + 192]);
        sd[threadIdx.x] = a;
    }
    __syncthreads();
    if (threadIdx.x < 16) {
        float4 a = sd[threadIdx.x];
        facc(a, sd[threadIdx.x + 16]);
        facc(a, sd[threadIdx.x + 32]);
        facc(a, sd[threadIdx.x + 48]);
        sd[threadIdx.x] = a;
    }
    __syncthreads();
    if (threadIdx.x < 4)
        *(float4*)&pcol[((size_t)g * nblk + bx) * 16 + threadIdx.x * 4] = sd[threadIdx.x];
}

// ---------------- cvec: coalesced reduce of pcol partials + tanh(mean @ Wa) ----------

__global__ void cvec_kernel(const float* __restrict__ pcol, int nb16, float n_inv,
                            const float* __restrict__ Wa, float* __restrict__ cvec) {
    int g = blockIdx.x;
    const float4* p4 = (const float4*)(pcol + (size_t)g * nb16 * 16);
    __shared__ float4 sd[TPB];
    __shared__ float cs[16];
    int c4 = threadIdx.x & 3;
    int row = threadIdx.x >> 2;
    float4 acc = make_float4(0.f, 0.f, 0.f, 0.f);
    for (int r = row; r < nb16; r += 64) facc(acc, p4[(size_t)r * 4 + c4]);
    sd[threadIdx.x] = acc;
    __syncthreads();
    if (threadIdx.x < 64) {
        float4 a = sd[threadIdx.x];
        facc(a, sd[threadIdx.x + 64]);
        facc(a, sd[threadIdx.x + 128]);
        facc(a, sd[threadIdx.x + 192]);
        sd[threadIdx.x] = a;
    }
    __syncthreads();
    if (threadIdx.x < 16) {
        float4 a = sd[threadIdx.x];
        facc(a, sd[threadIdx.x + 16]);
        facc(a, sd[threadIdx.x + 32]);
        facc(a, sd[threadIdx.x + 48]);
        sd[threadIdx.x] = a;
    }
    __syncthreads();
    if (threadIdx.x < 4) {
        float4 a = sd[threadIdx.x];
        facc(a, sd[threadIdx.x + 4]);
        facc(a, sd[threadIdx.x + 8]);
        facc(a, sd[threadIdx.x + 12]);
        cs[threadIdx.x * 4 + 0] = a.x * n_inv;
        cs[threadIdx.x * 4 + 1] = a.y * n_inv;
        cs[threadIdx.x * 4 + 2] = a.z * n_inv;
        cs[threadIdx.x * 4 + 3] = a.w * n_inv;
    }
    __syncthreads();
    if (threadIdx.x < 16) {
        float acc2 = 0.f;
#pragma unroll
        for (int i = 0; i < 16; i++) acc2 += cs[i] * Wa[i * 16 + threadIdx.x];
        cvec[g * 16 + threadIdx.x] = tanhf(acc2);
    }
}

// ---------------- attention pooling (per-block partials, no atomics) ----------------

__global__ void pool_kernel(const float* __restrict__ H0, const float* __restrict__ H1, int n,
                            const float* __restrict__ cvec, float* __restrict__ ppool) {
    int g = blockIdx.y;
    const float* H = g ? H1 : H0;
    int c = threadIdx.x & 15;
    float cv = cvec[g * 16 + c];
    int w = (blockIdx.x * blockDim.x + threadIdx.x) / 16;
    int stride = (gridDim.x * blockDim.x) / 16;
    float acc = 0.f;
    for (int node = w; node < n; node += stride) {
        float x = H[(size_t)node * 16 + c];
        float p = x * cv;
        p += __shfl_xor(p, 1, 16);
        p += __shfl_xor(p, 2, 16);
        p += __shfl_xor(p, 4, 16);
        p += __shfl_xor(p, 8, 16);
        float s = 1.f / (1.f + __expf(-p));
        acc += s * x;
    }
    __shared__ float sdata[TPB];
    sdata[threadIdx.x] = acc;
    __syncthreads();
    if (threadIdx.x < 16) {
        float s = 0.f;
        for (int t = threadIdx.x; t < TPB; t += 16) s += sdata[t];
        ppool[((size_t)g * gridDim.x + blockIdx.x) * 16 + threadIdx.x] = s;
    }
}

// ---------------- final: parallel reduce of pool partials + tensor-network scoring ----

__global__ void final_kernel(const float* __restrict__ ppool, int nbp,
                             const float* __restrict__ Wt, const float* __restrict__ Wb,
                             const float* __restrict__ bt, const float* __restrict__ Wfc,
                             const float* __restrict__ bfc, const float* __restrict__ Wsc,
                             const float* __restrict__ bsc, float* __restrict__ out) {
    __shared__ float4 sd4[TPB];
    __shared__ float rep[32], part[TPB], scores[16], tvec[16];
    int t = threadIdx.x;
    {
        const float4* p4 = (const float4*)ppool;
        int g = t >> 7;
        int r0 = (t >> 2) & 31;
        int c4 = t & 3;
        float4 acc = make_float4(0.f, 0.f, 0.f, 0.f);
        for (int r = r0; r < nbp; r += 32)
            facc(acc, p4[((size_t)g * nbp + r) * 4 + c4]);
        sd4[t] = acc;
        __syncthreads();
        for (int st = 16; st >= 1; st >>= 1) {
            if (r0 < st) facc(sd4[t], sd4[t + st * 4]);
            __syncthreads();
        }
        if (r0 == 0) {
            float4 a = sd4[t];
            rep[g * 16 + c4 * 4 + 0] = a.x;
            rep[g * 16 + c4 * 4 + 1] = a.y;
            rep[g * 16 + c4 * 4 + 2] = a.z;
            rep[g * 16 + c4 * 4 + 3] = a.w;
        }
        __syncthreads();
    }
    {
        int p = t >> 4, tt = t & 15;
        float b = 0.f;
#pragma unroll
        for (int q = 0; q < 16; q++)
            b += rep[q] * Wt[(q * 16 + p) * 16 + tt];
        part[t] = b * rep[16 + p];
    }
    __syncthreads();
    if (t < 16) {
        float bil = 0.f;
#pragma unroll
        for (int p = 0; p < 16; p++) bil += part[p * 16 + t];
        float blk = 0.f;
#pragma unroll
        for (int m = 0; m < 16; m++)
            blk += Wb[t * 32 + m] * rep[m] + Wb[t * 32 + 16 + m] * rep[16 + m];
        scores[t] = fmaxf(bil + blk + bt[t], 0.f);
    }
    __syncthreads();
    if (t < 16) {
        float acc = bfc[t];
#pragma unroll
        for (int k = 0; k < 16; k++) acc += scores[k] * Wfc[k * 16 + t];
        tvec[t] = tanhf(acc);
    }
    __syncthreads();
    if (t == 0) {
        float acc = bsc[0];
#pragma unroll
        for (int j = 0; j < 16; j++) acc += tvec[j] * Wsc[j];
        out[0] = 1.f / (1.f + __expf(-acc));
    }
}

// ---------------- launcher ----------------

extern "C" void kernel_launch(void* const* d_in, const int* in_sizes, int n_in,
                              void* d_out, int out_size, void* d_ws, size_t ws_size,
                              hipStream_t stream) {
    const float* X1 = (const float*)d_in[0];
    const float* X2 = (const float*)d_in[1];
    const int* edges1 = (const int*)d_in[2];
    const int* edges2 = (const int*)d_in[3];
    const float* W1 = (const float*)d_in[4];
    const float* b1 = (const float*)d_in[5];
    const float* W2 = (const float*)d_in[6];
    const float* b2 = (const float*)d_in[7];
    const float* W3 = (const float*)d_in[8];
    const float* b3 = (const float*)d_in[9];
    const float* Wa = (const float*)d_in[10];
    const float* Wt = (const float*)d_in[11];
    const float* Wb = (const float*)d_in[12];
    const float* bt = (const float*)d_in[13];
    const float* Wfc = (const float*)d_in[14];
    const float* bfc = (const float*)d_in[15];
    const float* Wsc = (const float*)d_in[16];
    const float* bsc = (const float*)d_in[17];
    float* out = (float*)d_out;

    const int N = in_sizes[0] / 96;
    const int E = in_sizes[2] / 2;
    const int NBUK = (N + BW - 1) / BW;  // buckets (must be <= 1024)
    int cap = ((2 * (E / NBUK)) + 255) & ~255;  // bucket capacity: 2x average, safe
    if (cap < 256) cap = 256;

    char* ws = (char*)d_ws;
    size_t o = 0;
    auto alloc = [&](size_t bytes) {
        void* p = ws + o;
        o += (bytes + 255) & ~(size_t)255;
        return p;
    };
    int* bcur = (int*)alloc((size_t)2 * 1024 * 4);
    int* soff0 = (int*)alloc((size_t)N * 4);
    int* soff1 = (int*)alloc((size_t)N * 4);
    int* eoff0 = (int*)alloc((size_t)N * 4);
    int* eoff1 = (int*)alloc((size_t)N * 4);
    int* col0 = (int*)alloc((size_t)NBUK * cap * 4);
    int* col1 = (int*)alloc((size_t)NBUK * cap * 4);
    int* ebuf0 = (int*)alloc((size_t)NBUK * cap * 4);
    int* ebuf1 = (int*)alloc((size_t)NBUK * cap * 4);
    float* dinv0 = (float*)alloc((size_t)N * 4);
    float* dinv1 = (float*)alloc((size_t)N * 4);
    u16* hwbA0 = (u16*)alloc((size_t)N * 64 * 2);  // layer-1 payload planes [2][N][32]
    u16* hwbA1 = (u16*)alloc((size_t)N * 64 * 2);
    u16* hwbH0 = (u16*)alloc((size_t)N * 64 * 2);  // relu'd H1 (contiguous 64ch rows)
    u16* hwbH1 = (u16*)alloc((size_t)N * 64 * 2);
    u16* hwbB0 = (u16*)alloc((size_t)N * 32 * 2);  // layer-2 payload
    u16* hwbB1 = (u16*)alloc((size_t)N * 32 * 2);
    u16* hwbC0 = (u16*)alloc((size_t)N * 16 * 2);  // layer-3 payload
    u16* hwbC1 = (u16*)alloc((size_t)N * 16 * 2);
    float* H30 = (float*)alloc((size_t)N * 16 * 4);  // H3 fp32 (pool input)
    float* H31 = (float*)alloc((size_t)N * 16 * 4);

    const int gB2 = (E + 4095) / 4096;
    const int g16 = ((size_t)N * 16 + TPB - 1) / TPB;  // aggs: 16 threads/node
    const int gSwz = 8 * ((g16 + 3) / 4);              // 4-XCD-per-graph swizzled grid
    const int gSplit = 8 * ((g16 + 1) / 2);            // 2-XCD-per-(graph,ch) grid
    const int gMM = (N + 63) / 64;
    const int gPool = 256;

    float* pcol = (float*)alloc((size_t)2 * g16 * 16 * 4);
    float* cvecArr = (float*)alloc(32 * 4);
    float* ppool = (float*)alloc((size_t)2 * gPool * 16 * 4);

    hipMemsetAsync(bcur, 0, (size_t)2 * 1024 * 4, stream);

    // capacity-bucket CSR build: scatter -> per-bucket finalize (no count/scan passes)
    bucket_scatter_kernel<<<dim3(gB2, 2), TPB, 0, stream>>>(edges1, edges2, E, bcur,
                                                            ebuf0, ebuf1, NBUK, cap);
    bucket_csr_kernel<<<dim3(NBUK, 2), TPB, 0, stream>>>(ebuf0, ebuf1, bcur, N, cap,
                                                         soff0, soff1, eoff0, eoff1,
                                                         dinv0, dinv1, col0, col1);

    // layer 1 matmul (MFMA 96->64), output channel-plane split
    matmul_kernel<96, 64, true><<<dim3(gMM, 2), TPB, 0, stream>>>(
        X1, X2, W1, dinv0, dinv1, hwbA0, hwbA1, N);
    // layer-1 agg: per-XCD (graph, channel-half) combo; writes relu'd bf16 H1
    agg_split_kernel<<<gSplit, TPB, 0, stream>>>(
        hwbA0, hwbA1, soff0, soff1, eoff0, eoff1, col0, col1, dinv0, dinv1, b1,
        hwbH0, hwbH1, N, g16);
    // layer-2 matmul (MFMA 64->32, bf16 input): hwbB = bf16(dinv * (H1 @ W2))
    matmul_bf_kernel<64, 32><<<dim3(gMM, 2), TPB, 0, stream>>>(
        hwbH0, hwbH1, W2, dinv0, dinv1, hwbB0, hwbB1, N);
    // layer-2 agg + fused layer-3 MFMA matmul (32 -> H2 -> @W3 -> 16 bf16)
    agg_mm_kernel<32, 2, 16><<<gSwz, TPB, 0, stream>>>(
        hwbB0, hwbB1, soff0, soff1, eoff0, eoff1, col0, col1, dinv0, dinv1, b2, W3,
        hwbC0, hwbC1, N, g16);
    // layer-3 agg (writes H3 fp32 + colsum partials)
    agg16_kernel<<<gSwz, TPB, 0, stream>>>(
        hwbC0, hwbC1, soff0, soff1, eoff0, eoff1, col0, col1, dinv0, dinv1, b3,
        H30, H31, pcol, N, g16);

    // attention pooling + scoring
    cvec_kernel<<<2, TPB, 0, stream>>>(pcol, g16, 1.0f / (float)N, Wa, cvecArr);
    pool_kernel<<<dim3(gPool, 2), TPB, 0, stream>>>(H30, H31, N, cvecArr, ppool);
    final_kernel<<<1, 256, 0, stream>>>(ppool, gPool, Wt, Wb, bt, Wfc, bfc, Wsc, bsc, out);
}

// Round 5
// 256.708 us; speedup vs baseline: 1.0592x; 1.0592x over previous
//
#include <hip/hip_runtime.h>
#include <hip/hip_bf16.h>

#define TPB 256
#define SH 6
#define BW 64  // nodes per bucket = 1<<SH; NBUK must be <= 1024 (N <= 65536)

typedef unsigned short u16;
typedef __attribute__((ext_vector_type(8))) __bf16 bf16x8;  // MFMA A/B frag (4 VGPRs)
typedef __attribute__((ext_vector_type(4))) float f32x4;    // MFMA C/D frag

// bf16 helpers: payload stored as bf16 (halves gather BW), accumulate in fp32.
__device__ __forceinline__ u16 f_to_bf(float f) {
    unsigned u = __float_as_uint(f);
    return (u16)((u + 0x7fff + ((u >> 16) & 1)) >> 16);  // RNE
}
__device__ __forceinline__ void facc(float4& a, float4 v) {
    a.x += v.x; a.y += v.y; a.z += v.z; a.w += v.w;
}

// XCD-aware block swizzle (4 XCDs per graph): blk&7 = XCD on MI355X.
__device__ __forceinline__ bool swz_block(int nblk, int& g, int& bx) {
    int blk = blockIdx.x;
    int j = blk & 7;
    g = j >> 2;
    bx = (blk >> 3) * 4 + (j & 3);
    return bx < nblk;
}

// ---- 16B/lane paired-edge gather ----
// Group of 2*CHUNKS lanes tiles (2 edges) x (C/8 16B-chunks). Per 8-edge batch:
// 4 col loads (per-lane-distinct addr -> ONE wave-instr each, no 16x redundancy)
// + 4 uint4 gathers = 8 VMEM wave-instrs vs 16 in the 8B/lane scheme. Address
// VALU halved. acc[8] fp32 per lane (its 8 channels).
__device__ __forceinline__ void acc8_add(float* __restrict__ a, uint4 d) {
    a[0] += __uint_as_float(d.x << 16);
    a[1] += __uint_as_float(d.x & 0xffff0000u);
    a[2] += __uint_as_float(d.y << 16);
    a[3] += __uint_as_float(d.y & 0xffff0000u);
    a[4] += __uint_as_float(d.z << 16);
    a[5] += __uint_as_float(d.z & 0xffff0000u);
    a[6] += __uint_as_float(d.w << 16);
    a[7] += __uint_as_float(d.w & 0xffff0000u);
}

template <int C>
__device__ __forceinline__ void gather_sum16(const u16* __restrict__ HW,
                                             const int* __restrict__ col,
                                             int e, int c8, int ps, int pe,
                                             float* __restrict__ acc) {
    int p = ps;
    for (; p + 8 <= pe; p += 8) {
        int j[4];
        uint4 d[4];
#pragma unroll
        for (int r = 0; r < 4; r++) j[r] = col[p + 2 * r + e];
#pragma unroll
        for (int r = 0; r < 4; r++) d[r] = *(const uint4*)&HW[(size_t)j[r] * C + c8 * 8];
#pragma unroll
        for (int r = 0; r < 4; r++) acc8_add(acc, d[r]);
    }
    for (; p + 2 <= pe; p += 2) {
        int j = col[p + e];
        acc8_add(acc, *(const uint4*)&HW[(size_t)j * C + c8 * 8]);
    }
    if (p < pe && e == 0) {
        int j = col[p];
        acc8_add(acc, *(const uint4*)&HW[(size_t)j * C + c8 * 8]);
    }
}

__device__ __forceinline__ void red8(float* __restrict__ a, int mask, int width) {
#pragma unroll
    for (int i = 0; i < 8; i++) a[i] += __shfl_xor(a[i], mask, width);
}

// ---------------- capacity-bucket CSR build (no count/scan passes) ----------------

__global__ void bucket_scatter_kernel(const int* __restrict__ e0, const int* __restrict__ e1,
                                      int E, int* __restrict__ bcur,
                                      int* __restrict__ ebuf0, int* __restrict__ ebuf1,
                                      int nbuk, int cap) {
    int g = blockIdx.y;
    const int* src = g ? e1 : e0;
    const int* dst = src + E;
    int* ebuf = g ? ebuf1 : ebuf0;
    int* bu = bcur + g * 1024;
    __shared__ int hist[1024];
    for (int t = threadIdx.x; t < 1024; t += TPB) hist[t] = 0;
    __syncthreads();
    int base = blockIdx.x * 4096;
    int pk[16], bk[16], rk[16];
#pragma unroll
    for (int k = 0; k < 16; k++) {
        int e = base + k * TPB + (int)threadIdx.x;
        bk[k] = -1;
        if (e < E) {
            int s = src[e], d = dst[e];
            int b = d >> SH;
            bk[k] = b;
            pk[k] = (s << SH) | (d & (BW - 1));
            rk[k] = atomicAdd(&hist[b], 1);
        }
    }
    __syncthreads();
    for (int t = threadIdx.x; t < nbuk; t += TPB) {
        int h = hist[t];
        hist[t] = h ? atomicAdd(&bu[t], h) : 0;
    }
    __syncthreads();
#pragma unroll
    for (int k = 0; k < 16; k++)
        if (bk[k] >= 0) {
            int pos = hist[bk[k]] + rk[k];
            if (pos < cap) ebuf[(size_t)bk[k] * cap + pos] = pk[k];
        }
}

// Per-bucket: histogram -> local scan -> soff/eoff/dinv -> fill col (bucket-local).
__global__ void bucket_csr_kernel(const int* __restrict__ ebuf0, const int* __restrict__ ebuf1,
                                  const int* __restrict__ bcur, int n, int cap,
                                  int* __restrict__ soff0, int* __restrict__ soff1,
                                  int* __restrict__ eoff0, int* __restrict__ eoff1,
                                  float* __restrict__ dinv0, float* __restrict__ dinv1,
                                  int* __restrict__ col0, int* __restrict__ col1) {
    int g = blockIdx.y;
    int b = blockIdx.x;
    const int* ebuf = g ? ebuf1 : ebuf0;
    int* soff = g ? soff1 : soff0;
    int* eoff = g ? eoff1 : eoff0;
    float* dinv = g ? dinv1 : dinv0;
    int* col = g ? col1 : col0;
    __shared__ int h[BW], nb[BW], nrank[BW];
    int tid = threadIdx.x;
    if (tid < BW) h[tid] = 0;
    __syncthreads();
    int s = b * cap;
    int cnt = min(bcur[g * 1024 + b], cap);
    int e = s + cnt;
    for (int i = s + tid; i < e; i += TPB)
        atomicAdd(&h[ebuf[i] & (BW - 1)], 1);
    __syncthreads();
    if (tid < BW) {
        int v = h[tid];
        int x = v;
        for (int d = 1; d < BW; d <<= 1) {
            int u = __shfl_up(x, d, 64);
            if (tid >= d) x += u;
        }
        int base = s + x - v;  // exclusive prefix within bucket region
        nb[tid] = base;
        nrank[tid] = 0;
        int node = b * BW + tid;
        if (node < n) {
            soff[node] = base;
            eoff[node] = base + v;
            dinv[node] = rsqrtf((float)v + 1.0f);
        }
    }
    __syncthreads();
    for (int i = s + tid; i < e; i += TPB) {
        int p = ebuf[i];
        int lo = p & (BW - 1);
        int r = atomicAdd(&nrank[lo], 1);
        col[nb[lo] + r] = p >> SH;
    }
}

// ---------------- dense matmul via MFMA: Y = bf16( dinv[n] * (X @ W) ) ----------

template <int CIN, int COUT>
__global__ void matmul_kernel(const float* __restrict__ X0, const float* __restrict__ X1,
                              const float* __restrict__ W,
                              const float* __restrict__ dinv0, const float* __restrict__ dinv1,
                              u16* __restrict__ Y0, u16* __restrict__ Y1, int n) {
    constexpr int CINP = CIN + 8;
    constexpr int NT = COUT / 16;
    constexpr int KT = CIN / 32;
    __shared__ u16 Xs[64 * CINP];
    __shared__ u16 Wt[COUT * CINP];

    int g = blockIdx.y;
    const float* X = g ? X1 : X0;
    const float* dinv = g ? dinv1 : dinv0;
    u16* Y = g ? Y1 : Y0;
    int nb0 = blockIdx.x * 64;

    for (int i = threadIdx.x; i < 64 * (CIN / 4); i += TPB) {
        int nn = i / (CIN / 4), kc = i % (CIN / 4);
        float4 v = make_float4(0.f, 0.f, 0.f, 0.f);
        if (nb0 + nn < n) v = *(const float4*)&X[(size_t)(nb0 + nn) * CIN + 4 * kc];
        ushort4 b;
        b.x = f_to_bf(v.x); b.y = f_to_bf(v.y); b.z = f_to_bf(v.z); b.w = f_to_bf(v.w);
        *(ushort4*)&Xs[nn * CINP + 4 * kc] = b;
    }
    for (int i = threadIdx.x; i < CIN * (COUT / 4); i += TPB) {
        int k = i / (COUT / 4), nc4 = i % (COUT / 4);
        float4 v = *(const float4*)&W[(size_t)k * COUT + 4 * nc4];
        Wt[(4 * nc4 + 0) * CINP + k] = f_to_bf(v.x);
        Wt[(4 * nc4 + 1) * CINP + k] = f_to_bf(v.y);
        Wt[(4 * nc4 + 2) * CINP + k] = f_to_bf(v.z);
        Wt[(4 * nc4 + 3) * CINP + k] = f_to_bf(v.w);
    }
    __syncthreads();

    int lane = threadIdx.x & 63;
    int w = threadIdx.x >> 6;
    int m = lane & 15;
    int quad = lane >> 4;

    f32x4 acc[NT];
#pragma unroll
    for (int t = 0; t < NT; t++) acc[t] = (f32x4){0.f, 0.f, 0.f, 0.f};
#pragma unroll
    for (int kt = 0; kt < KT; kt++) {
        int k0 = kt * 32 + quad * 8;
        bf16x8 a = *(const bf16x8*)&Xs[(w * 16 + m) * CINP + k0];
#pragma unroll
        for (int t = 0; t < NT; t++) {
            bf16x8 b = *(const bf16x8*)&Wt[(t * 16 + m) * CINP + k0];
            acc[t] = __builtin_amdgcn_mfma_f32_16x16x32_bf16(a, b, acc[t], 0, 0, 0);
        }
    }
#pragma unroll
    for (int r = 0; r < 4; r++) {
        int node = nb0 + w * 16 + quad * 4 + r;
        if (node < n) {
            float d = dinv[node];
#pragma unroll
            for (int t = 0; t < NT; t++)
                Y[(size_t)node * COUT + t * 16 + m] = f_to_bf(acc[t][r] * d);
        }
    }
}

// ------- fused GCN agg (16B/lane paired-edge gather) + MFMA next-layer matmul -------
// Block = 16 nodes (TPN=16 threads/node). Lane tiling per slice-group:
// (e in {0,1}) x (c8 in [0,C/8)). Gather+relu -> bf16 H rows in LDS; MFMA epilogue
// computes Y = bf16(dinv * (H @ W2)).

template <int C, int SPLIT, int COUT2>
__global__ __launch_bounds__(TPB, 2)
void agg_mm_kernel(const u16* __restrict__ HW0, const u16* __restrict__ HW1,
                   const int* __restrict__ soff0, const int* __restrict__ soff1,
                   const int* __restrict__ eoff0, const int* __restrict__ eoff1,
                   const int* __restrict__ col0, const int* __restrict__ col1,
                   const float* __restrict__ dinv0, const float* __restrict__ dinv1,
                   const float* __restrict__ bias, const float* __restrict__ W2,
                   u16* __restrict__ Y0, u16* __restrict__ Y1, int n, int nblk) {
    constexpr int CHUNKS = C / 8;      // 16B chunks per row
    constexpr int GRP = 2 * CHUNKS;    // lanes per slice-group
    constexpr int TPN = GRP * SPLIT;   // 16
    constexpr int CP = C + 8;          // padded LDS row stride (u16), 16B-aligned rows
    constexpr int NT2 = COUT2 / 16;    // MFMA col-tiles
    constexpr int KT2 = C / 32;        // MFMA k-tiles
    __shared__ __align__(16) u16 HsB[16 * CP];
    __shared__ __align__(16) u16 WtB[COUT2 * CP];

    int g, bx;
    if (!swz_block(nblk, g, bx)) return;
    const u16* HW = g ? HW1 : HW0;
    const int* soff = g ? soff1 : soff0;
    const int* eoff = g ? eoff1 : eoff0;
    const int* col = g ? col1 : col0;
    const float* dinv = g ? dinv1 : dinv0;
    u16* Y = g ? Y1 : Y0;

    // stage W2 transposed (bf16) while gather loads are in flight
    for (int idx = threadIdx.x; idx < C * COUT2; idx += TPB) {
        int k = idx / COUT2, nc = idx % COUT2;
        WtB[nc * CP + k] = f_to_bf(W2[idx]);
    }

    int nl = threadIdx.x >> 4;
    int part = threadIdx.x & 15;
    int sp = part / GRP;
    int gl = part % GRP;
    int e = gl / CHUNKS;
    int c8 = gl % CHUNKS;
    int node = bx * 16 + nl;

    float acc[8];
#pragma unroll
    for (int i = 0; i < 8; i++) acc[i] = 0.f;
    float o8[8];
#pragma unroll
    for (int i = 0; i < 8; i++) o8[i] = 0.f;

    if (node < n) {
        int s = soff[node], en = eoff[node];
        int len = en - s;
        int chunk = (len + SPLIT - 1) / SPLIT;
        int ps = s + sp * chunk;
        int pe = min(ps + chunk, en);
        gather_sum16<C>(HW, col, e, c8, ps, pe, acc);
        red8(acc, CHUNKS, TPN);  // sum the 2 edge-lanes
#pragma unroll
        for (int m = GRP; m < TPN; m <<= 1) red8(acc, m, TPN);  // sum slices
        if (part < CHUNKS) {  // writer lane: holds chunk c8 = part
            float di = dinv[node];
            uint4 sv = *(const uint4*)&HW[(size_t)node * C + part * 8];
            float4 b0 = *(const float4*)&bias[part * 8];
            float4 b1 = *(const float4*)&bias[part * 8 + 4];
            o8[0] = fmaxf(di * (acc[0] + __uint_as_float(sv.x << 16)) + b0.x, 0.f);
            o8[1] = fmaxf(di * (acc[1] + __uint_as_float(sv.x & 0xffff0000u)) + b0.y, 0.f);
            o8[2] = fmaxf(di * (acc[2] + __uint_as_float(sv.y << 16)) + b0.z, 0.f);
            o8[3] = fmaxf(di * (acc[3] + __uint_as_float(sv.y & 0xffff0000u)) + b0.w, 0.f);
            o8[4] = fmaxf(di * (acc[4] + __uint_as_float(sv.z << 16)) + b1.x, 0.f);
            o8[5] = fmaxf(di * (acc[5] + __uint_as_float(sv.z & 0xffff0000u)) + b1.y, 0.f);
            o8[6] = fmaxf(di * (acc[6] + __uint_as_float(sv.w << 16)) + b1.z, 0.f);
            o8[7] = fmaxf(di * (acc[7] + __uint_as_float(sv.w & 0xffff0000u)) + b1.w, 0.f);
        }
    }
    if (part < CHUNKS) {  // zeros for tail nodes
        uint4 hv;
        hv.x = (unsigned)f_to_bf(o8[0]) | ((unsigned)f_to_bf(o8[1]) << 16);
        hv.y = (unsigned)f_to_bf(o8[2]) | ((unsigned)f_to_bf(o8[3]) << 16);
        hv.z = (unsigned)f_to_bf(o8[4]) | ((unsigned)f_to_bf(o8[5]) << 16);
        hv.w = (unsigned)f_to_bf(o8[6]) | ((unsigned)f_to_bf(o8[7]) << 16);
        *(uint4*)&HsB[nl * CP + part * 8] = hv;
    }
    __syncthreads();

    // MFMA epilogue: wave w computes 16 nodes x out-cols [w*16, w*16+16)
    int lane = threadIdx.x & 63;
    int w = threadIdx.x >> 6;
    if (w < NT2) {
        int m = lane & 15;
        int quad = lane >> 4;
        f32x4 ac = (f32x4){0.f, 0.f, 0.f, 0.f};
#pragma unroll
        for (int kt = 0; kt < KT2; kt++) {
            int k0 = kt * 32 + quad * 8;
            bf16x8 a = *(const bf16x8*)&HsB[m * CP + k0];
            bf16x8 b = *(const bf16x8*)&WtB[(w * 16 + m) * CP + k0];
            ac = __builtin_amdgcn_mfma_f32_16x16x32_bf16(a, b, ac, 0, 0, 0);
        }
        int base16 = bx * 16;
#pragma unroll
        for (int r = 0; r < 4; r++) {
            int onode = base16 + quad * 4 + r;
            if (onode < n)
                Y[(size_t)onode * COUT2 + w * 16 + m] = f_to_bf(ac[r] * dinv[onode]);
        }
    }
}

// Layer-3 aggregation (C=16, paired-edge 16B gather, SPLIT=4) + bf16 H3 out +
// per-block colsum partials (NO atomics).
__global__ __launch_bounds__(TPB, 2)
void agg16_kernel(const u16* __restrict__ HW0, const u16* __restrict__ HW1,
                  const int* __restrict__ soff0, const int* __restrict__ soff1,
                  const int* __restrict__ eoff0, const int* __restrict__ eoff1,
                  const int* __restrict__ col0, const int* __restrict__ col1,
                  const float* __restrict__ dinv0, const float* __restrict__ dinv1,
                  const float* __restrict__ bias,
                  u16* __restrict__ out0, u16* __restrict__ out1,
                  float* __restrict__ pcol, int n, int nblk) {
    int g, bx;
    if (!swz_block(nblk, g, bx)) return;
    const u16* HW = g ? HW1 : HW0;
    const int* soff = g ? soff1 : soff0;
    const int* eoff = g ? eoff1 : eoff0;
    const int* col = g ? col1 : col0;
    const float* dinv = g ? dinv1 : dinv0;
    u16* outp = g ? out1 : out0;

    int nl = threadIdx.x >> 4;
    int part = threadIdx.x & 15;
    int sp = part >> 2;       // 4 slices (GRP=4)
    int gl = part & 3;
    int e = gl >> 1;          // CHUNKS=2
    int c8 = gl & 1;
    int node = bx * 16 + nl;

    float acc[8];
#pragma unroll
    for (int i = 0; i < 8; i++) acc[i] = 0.f;
    float o8[8];
#pragma unroll
    for (int i = 0; i < 8; i++) o8[i] = 0.f;

    if (node < n) {
        int s = soff[node], en = eoff[node];
        int len = en - s;
        int chunk = (len + 3) >> 2;
        int ps = s + sp * chunk;
        int pe = min(ps + chunk, en);
        gather_sum16<16>(HW, col, e, c8, ps, pe, acc);
        red8(acc, 2, 16);
        red8(acc, 4, 16);
        red8(acc, 8, 16);
        if (part < 2) {
            float di = dinv[node];
            uint4 sv = *(const uint4*)&HW[(size_t)node * 16 + part * 8];
            float4 b0 = *(const float4*)&bias[part * 8];
            float4 b1 = *(const float4*)&bias[part * 8 + 4];
            o8[0] = di * (acc[0] + __uint_as_float(sv.x << 16)) + b0.x;
            o8[1] = di * (acc[1] + __uint_as_float(sv.x & 0xffff0000u)) + b0.y;
            o8[2] = di * (acc[2] + __uint_as_float(sv.y << 16)) + b0.z;
            o8[3] = di * (acc[3] + __uint_as_float(sv.y & 0xffff0000u)) + b0.w;
            o8[4] = di * (acc[4] + __uint_as_float(sv.z << 16)) + b1.x;
            o8[5] = di * (acc[5] + __uint_as_float(sv.z & 0xffff0000u)) + b1.y;
            o8[6] = di * (acc[6] + __uint_as_float(sv.w << 16)) + b1.z;
            o8[7] = di * (acc[7] + __uint_as_float(sv.w & 0xffff0000u)) + b1.w;
            uint4 hv;
            hv.x = (unsigned)f_to_bf(o8[0]) | ((unsigned)f_to_bf(o8[1]) << 16);
            hv.y = (unsigned)f_to_bf(o8[2]) | ((unsigned)f_to_bf(o8[3]) << 16);
            hv.z = (unsigned)f_to_bf(o8[4]) | ((unsigned)f_to_bf(o8[5]) << 16);
            hv.w = (unsigned)f_to_bf(o8[6]) | ((unsigned)f_to_bf(o8[7]) << 16);
            *(uint4*)&outp[(size_t)node * 16 + part * 8] = hv;
        }
    }
    // per-block colsum partial: lanes part<2 hold chunk (part*8..part*8+7)
    __shared__ float4 sa[TPB], sb[TPB];
    bool hold = (node < n) && (part < 2);
    sa[threadIdx.x] = hold ? make_float4(o8[0], o8[1], o8[2], o8[3])
                           : make_float4(0.f, 0.f, 0.f, 0.f);
    sb[threadIdx.x] = hold ? make_float4(o8[4], o8[5], o8[6], o8[7])
                           : make_float4(0.f, 0.f, 0.f, 0.f);
    __syncthreads();
    if (threadIdx.x < 64) {
        float4 a = sa[threadIdx.x], b = sb[threadIdx.x];
        facc(a, sa[threadIdx.x + 64]);  facc(b, sb[threadIdx.x + 64]);
        facc(a, sa[threadIdx.x + 128]); facc(b, sb[threadIdx.x + 128]);
        facc(a, sa[threadIdx.x + 192]); facc(b, sb[threadIdx.x + 192]);
        sa[threadIdx.x] = a; sb[threadIdx.x] = b;
    }
    __syncthreads();
    if (threadIdx.x < 16) {
        float4 a = sa[threadIdx.x], b = sb[threadIdx.x];
        facc(a, sa[threadIdx.x + 16]); facc(b, sb[threadIdx.x + 16]);
        facc(a, sa[threadIdx.x + 32]); facc(b, sb[threadIdx.x + 32]);
        facc(a, sa[threadIdx.x + 48]); facc(b, sb[threadIdx.x + 48]);
        sa[threadIdx.x] = a; sb[threadIdx.x] = b;
    }
    __syncthreads();
    if (threadIdx.x < 2) {
        float* dst = &pcol[((size_t)g * nblk + bx) * 16 + threadIdx.x * 8];
        *(float4*)&dst[0] = sa[threadIdx.x];
        *(float4*)&dst[4] = sb[threadIdx.x];
    }
}

// ---------------- cvec: coalesced reduce of pcol partials + tanh(mean @ Wa) ----------

__global__ void cvec_kernel(const float* __restrict__ pcol, int nb16, float n_inv,
                            const float* __restrict__ Wa, float* __restrict__ cvec) {
    int g = blockIdx.x;
    const float4* p4 = (const float4*)(pcol + (size_t)g * nb16 * 16);
    __shared__ float4 sd[TPB];
    __shared__ float cs[16];
    int c4 = threadIdx.x & 3;
    int row = threadIdx.x >> 2;
    float4 acc = make_float4(0.f, 0.f, 0.f, 0.f);
    for (int r = row; r < nb16; r += 64) facc(acc, p4[(size_t)r * 4 + c4]);
    sd[threadIdx.x] = acc;
    __syncthreads();
    if (threadIdx.x < 64) {
        float4 a = sd[threadIdx.x];
        facc(a, sd[threadIdx.x + 64]);
        facc(a, sd[threadIdx.x + 128]);
        facc(a, sd[threadIdx.x + 192]);
        sd[threadIdx.x] = a;
    }
    __syncthreads();
    if (threadIdx.x < 16) {
        float4 a = sd[threadIdx.x];
        facc(a, sd[threadIdx.x + 16]);
        facc(a, sd[threadIdx.x + 32]);
        facc(a, sd[threadIdx.x + 48]);
        sd[threadIdx.x] = a;
    }
    __syncthreads();
    if (threadIdx.x < 4) {
        float4 a = sd[threadIdx.x];
        facc(a, sd[threadIdx.x + 4]);
        facc(a, sd[threadIdx.x + 8]);
        facc(a, sd[threadIdx.x + 12]);
        cs[threadIdx.x * 4 + 0] = a.x * n_inv;
        cs[threadIdx.x * 4 + 1] = a.y * n_inv;
        cs[threadIdx.x * 4 + 2] = a.z * n_inv;
        cs[threadIdx.x * 4 + 3] = a.w * n_inv;
    }
    __syncthreads();
    if (threadIdx.x < 16) {
        float acc2 = 0.f;
#pragma unroll
        for (int i = 0; i < 16; i++) acc2 += cs[i] * Wa[i * 16 + threadIdx.x];
        cvec[g * 16 + threadIdx.x] = tanhf(acc2);
    }
}

// ---------------- attention pooling (bf16 H3, per-block partials) ----------------

__global__ void pool_kernel(const u16* __restrict__ H0, const u16* __restrict__ H1, int n,
                            const float* __restrict__ cvec, float* __restrict__ ppool) {
    int g = blockIdx.y;
    const u16* H = g ? H1 : H0;
    int c = threadIdx.x & 15;
    float cv = cvec[g * 16 + c];
    int w = (blockIdx.x * blockDim.x + threadIdx.x) / 16;
    int stride = (gridDim.x * blockDim.x) / 16;
    float acc = 0.f;
    for (int node = w; node < n; node += stride) {
        float x = __uint_as_float((unsigned)H[(size_t)node * 16 + c] << 16);
        float p = x * cv;
        p += __shfl_xor(p, 1, 16);
        p += __shfl_xor(p, 2, 16);
        p += __shfl_xor(p, 4, 16);
        p += __shfl_xor(p, 8, 16);
        float s = 1.f / (1.f + __expf(-p));
        acc += s * x;
    }
    __shared__ float sdata[TPB];
    sdata[threadIdx.x] = acc;
    __syncthreads();
    if (threadIdx.x < 16) {
        float s = 0.f;
        for (int t = threadIdx.x; t < TPB; t += 16) s += sdata[t];
        ppool[((size_t)g * gridDim.x + blockIdx.x) * 16 + threadIdx.x] = s;
    }
}

// ---------------- final: parallel reduce of pool partials + tensor-network scoring ----

__global__ void final_kernel(const float* __restrict__ ppool, int nbp,
                             const float* __restrict__ Wt, const float* __restrict__ Wb,
                             const float* __restrict__ bt, const float* __restrict__ Wfc,
                             const float* __restrict__ bfc, const float* __restrict__ Wsc,
                             const float* __restrict__ bsc, float* __restrict__ out) {
    __shared__ float4 sd4[TPB];
    __shared__ float rep[32], part[TPB], scores[16], tvec[16];
    int t = threadIdx.x;
    {
        const float4* p4 = (const float4*)ppool;
        int g = t >> 7;
        int r0 = (t >> 2) & 31;
        int c4 = t & 3;
        float4 acc = make_float4(0.f, 0.f, 0.f, 0.f);
        for (int r = r0; r < nbp; r += 32)
            facc(acc, p4[((size_t)g * nbp + r) * 4 + c4]);
        sd4[t] = acc;
        __syncthreads();
        for (int st = 16; st >= 1; st >>= 1) {
            if (r0 < st) facc(sd4[t], sd4[t + st * 4]);
            __syncthreads();
        }
        if (r0 == 0) {
            float4 a = sd4[t];
            rep[g * 16 + c4 * 4 + 0] = a.x;
            rep[g * 16 + c4 * 4 + 1] = a.y;
            rep[g * 16 + c4 * 4 + 2] = a.z;
            rep[g * 16 + c4 * 4 + 3] = a.w;
        }
        __syncthreads();
    }
    {
        int p = t >> 4, tt = t & 15;
        float b = 0.f;
#pragma unroll
        for (int q = 0; q < 16; q++)
            b += rep[q] * Wt[(q * 16 + p) * 16 + tt];
        part[t] = b * rep[16 + p];
    }
    __syncthreads();
    if (t < 16) {
        float bil = 0.f;
#pragma unroll
        for (int p = 0; p < 16; p++) bil += part[p * 16 + t];
        float blk = 0.f;
#pragma unroll
        for (int m = 0; m < 16; m++)
            blk += Wb[t * 32 + m] * rep[m] + Wb[t * 32 + 16 + m] * rep[16 + m];
        scores[t] = fmaxf(bil + blk + bt[t], 0.f);
    }
    __syncthreads();
    if (t < 16) {
        float acc = bfc[t];
#pragma unroll
        for (int k = 0; k < 16; k++) acc += scores[k] * Wfc[k * 16 + t];
        tvec[t] = tanhf(acc);
    }
    __syncthreads();
    if (t == 0) {
        float acc = bsc[0];
#pragma unroll
        for (int j = 0; j < 16; j++) acc += tvec[j] * Wsc[j];
        out[0] = 1.f / (1.f + __expf(-acc));
    }
}

// ---------------- launcher ----------------

extern "C" void kernel_launch(void* const* d_in, const int* in_sizes, int n_in,
                              void* d_out, int out_size, void* d_ws, size_t ws_size,
                              hipStream_t stream) {
    const float* X1 = (const float*)d_in[0];
    const float* X2 = (const float*)d_in[1];
    const int* edges1 = (const int*)d_in[2];
    const int* edges2 = (const int*)d_in[3];
    const float* W1 = (const float*)d_in[4];
    const float* b1 = (const float*)d_in[5];
    const float* W2 = (const float*)d_in[6];
    const float* b2 = (const float*)d_in[7];
    const float* W3 = (const float*)d_in[8];
    const float* b3 = (const float*)d_in[9];
    const float* Wa = (const float*)d_in[10];
    const float* Wt = (const float*)d_in[11];
    const float* Wb = (const float*)d_in[12];
    const float* bt = (const float*)d_in[13];
    const float* Wfc = (const float*)d_in[14];
    const float* bfc = (const float*)d_in[15];
    const float* Wsc = (const float*)d_in[16];
    const float* bsc = (const float*)d_in[17];
    float* out = (float*)d_out;

    const int N = in_sizes[0] / 96;
    const int E = in_sizes[2] / 2;
    const int NBUK = (N + BW - 1) / BW;  // buckets (must be <= 1024)
    int cap = ((2 * (E / NBUK)) + 255) & ~255;  // bucket capacity: 2x average, safe
    if (cap < 256) cap = 256;

    char* ws = (char*)d_ws;
    size_t o = 0;
    auto alloc = [&](size_t bytes) {
        void* p = ws + o;
        o += (bytes + 255) & ~(size_t)255;
        return p;
    };
    int* bcur = (int*)alloc((size_t)2 * 1024 * 4);
    int* soff0 = (int*)alloc((size_t)N * 4);
    int* soff1 = (int*)alloc((size_t)N * 4);
    int* eoff0 = (int*)alloc((size_t)N * 4);
    int* eoff1 = (int*)alloc((size_t)N * 4);
    int* col0 = (int*)alloc((size_t)NBUK * cap * 4);
    int* col1 = (int*)alloc((size_t)NBUK * cap * 4);
    int* ebuf0 = (int*)alloc((size_t)NBUK * cap * 4);
    int* ebuf1 = (int*)alloc((size_t)NBUK * cap * 4);
    float* dinv0 = (float*)alloc((size_t)N * 4);
    float* dinv1 = (float*)alloc((size_t)N * 4);
    u16* hwbA0 = (u16*)alloc((size_t)N * 64 * 2);  // layer-1 payload
    u16* hwbA1 = (u16*)alloc((size_t)N * 64 * 2);
    u16* hwbB0 = (u16*)alloc((size_t)N * 32 * 2);  // layer-2 payload
    u16* hwbB1 = (u16*)alloc((size_t)N * 32 * 2);
    u16* hwbC0 = (u16*)alloc((size_t)N * 16 * 2);  // layer-3 payload
    u16* hwbC1 = (u16*)alloc((size_t)N * 16 * 2);
    u16* H30 = (u16*)alloc((size_t)N * 16 * 2);  // H3 bf16 (pool input)
    u16* H31 = (u16*)alloc((size_t)N * 16 * 2);

    const int gB2 = (E + 4095) / 4096;
    const int g16 = ((size_t)N * 16 + TPB - 1) / TPB;  // aggs: 16 threads/node
    const int gSwz = 8 * ((g16 + 3) / 4);              // 4-XCD-per-graph swizzled grid
    const int gMM = (N + 63) / 64;
    const int gPool = 256;

    float* pcol = (float*)alloc((size_t)2 * g16 * 16 * 4);
    float* cvecArr = (float*)alloc(32 * 4);
    float* ppool = (float*)alloc((size_t)2 * gPool * 16 * 4);

    hipMemsetAsync(bcur, 0, (size_t)2 * 1024 * 4, stream);

    // capacity-bucket CSR build: scatter -> per-bucket finalize (no count/scan passes)
    bucket_scatter_kernel<<<dim3(gB2, 2), TPB, 0, stream>>>(edges1, edges2, E, bcur,
                                                            ebuf0, ebuf1, NBUK, cap);
    bucket_csr_kernel<<<dim3(NBUK, 2), TPB, 0, stream>>>(ebuf0, ebuf1, bcur, N, cap,
                                                         soff0, soff1, eoff0, eoff1,
                                                         dinv0, dinv1, col0, col1);

    // layer 1 matmul (MFMA 96->64)
    matmul_kernel<96, 64><<<dim3(gMM, 2), TPB, 0, stream>>>(X1, X2, W1, dinv0, dinv1,
                                                            hwbA0, hwbA1, N);
    // layer-1 agg + fused layer-2 MFMA matmul (64 -> H1 -> @W2 -> 32 bf16)
    agg_mm_kernel<64, 1, 32><<<gSwz, TPB, 0, stream>>>(
        hwbA0, hwbA1, soff0, soff1, eoff0, eoff1, col0, col1, dinv0, dinv1, b1, W2,
        hwbB0, hwbB1, N, g16);
    // layer-2 agg + fused layer-3 MFMA matmul (32 -> H2 -> @W3 -> 16 bf16)
    agg_mm_kernel<32, 2, 16><<<gSwz, TPB, 0, stream>>>(
        hwbB0, hwbB1, soff0, soff1, eoff0, eoff1, col0, col1, dinv0, dinv1, b2, W3,
        hwbC0, hwbC1, N, g16);
    // layer-3 agg (writes H3 bf16 + colsum partials)
    agg16_kernel<<<gSwz, TPB, 0, stream>>>(
        hwbC0, hwbC1, soff0, soff1, eoff0, eoff1, col0, col1, dinv0, dinv1, b3,
        H30, H31, pcol, N, g16);

    // attention pooling + scoring
    cvec_kernel<<<2, TPB, 0, stream>>>(pcol, g16, 1.0f / (float)N, Wa, cvecArr);
    pool_kernel<<<dim3(gPool, 2), TPB, 0, stream>>>(H30, H31, N, cvecArr, ppool);
    final_kernel<<<1, 256, 0, stream>>>(ppool, gPool, Wt, Wb, bt, Wfc, bfc, Wsc, bsc, out);
}